// Round 15
// baseline (344.058 us; speedup 1.0000x reference)
//
#include <hip/hip_runtime.h>
#include <hip/hip_bf16.h>

#define BATCH   512
#define INDIM   768
#define HID     256
#define NGEN    4095
#define NOBS    15
#define OUTDIM  512
#define DIM     64

typedef __hip_bfloat16 bf16;

// static device scratch: no reliance on ws_size
__device__ int   g_isf32;
__device__ float g_theta[(size_t)BATCH*NGEN];
__device__ float g_q[BATCH*NOBS];

__device__ __forceinline__ float tof(bf16 v){ return __bfloat162float(v); }
__device__ __forceinline__ float silu(float x){ return x / (1.f + __expf(-x)); }

template<bool F32>
__device__ __forceinline__ float LD(const void* p, size_t i){
  if(F32) return ((const float*)p)[i];
  else    return tof(((const bf16*)p)[i]);
}

// put bit p of x at bit 2p (6-bit input)
__device__ __forceinline__ unsigned spread6(unsigned x){
  return (x&1u) | ((x&2u)<<1) | ((x&4u)<<2) | ((x&8u)<<3) | ((x&16u)<<4) | ((x&32u)<<5);
}

__constant__ int c_WA[15] = {0,0,0,0,0,1,1,1,1,2,2,2,3,3,4};
__constant__ int c_WB[15] = {1,2,3,4,5,2,3,4,5,3,4,5,4,5,5};
__constant__ int c_Lt[6]  = {1,2,2,3,3,3};
__constant__ int c_Kt[6]  = {0,0,1,0,1,2};

// ---- dtype sniffer (UNCHANGED; stays the FIRST kernel) ----
__global__ __launch_bounds__(256) void k_detect(const unsigned* __restrict__ w1raw){
  __shared__ int sh[256];
  const int t = threadIdx.x;
  int c = 0;
  for(int i=t;i<1024;i+=256){
    unsigned ub = (w1raw[i]>>8) & 0x7Fu;
    if(ub>=0x30u && ub<=0x3Fu) c++;
  }
  sh[t] = c;
  __syncthreads();
  for(int s=128;s>0;s>>=1){
    if(t<s) sh[t] += sh[t+s];
    __syncthreads();
  }
  if(t==0) g_isf32 = (sh[0] < 512) ? 1 : 0;
}

// ---------------- enc MLP (UNCHANGED R13 body) ----------------
template<bool F32>
__device__ void enc_body(const void* __restrict__ x, const void* __restrict__ W1,
                         const void* __restrict__ b1, const void* __restrict__ W2,
                         const void* __restrict__ b2,
                         float (*xl_t)[4], float (*hl_t)[4]){
  const int t  = threadIdx.x;
  const int b0 = (blockIdx.x >> 3) * 4;            // row group 0..127
  const int c0 = (blockIdx.x & 7) * 512;           // col group 0..7

  #pragma unroll
  for(int r=0;r<4;r++)
    for(int k=t;k<INDIM;k+=256) xl_t[k][r] = LD<F32>(x,(size_t)(b0+r)*INDIM+k);
  __syncthreads();

  {
    float acc1[4]={0.f,0.f,0.f,0.f};
    for(int k0=0;k0<INDIM;k0+=8){
      float wv[8];
      #pragma unroll
      for(int u=0;u<8;u++) wv[u] = LD<F32>(W1,(size_t)(k0+u)*HID+t);
      #pragma unroll
      for(int u=0;u<8;u++){
        float4 xa = *(const float4*)&xl_t[k0+u][0];
        float w = wv[u];
        acc1[0]+=xa.x*w; acc1[1]+=xa.y*w; acc1[2]+=xa.z*w; acc1[3]+=xa.w*w;
      }
    }
    float bb = LD<F32>(b1,t);
    #pragma unroll
    for(int r=0;r<4;r++) hl_t[t][r] = silu(acc1[r]+bb);
  }
  __syncthreads();

  const int colA = c0 + t;
  const int colB = c0 + 256 + t;
  const bool okB = (colB < NGEN);
  float acc[4][2];
  {
    float bva = LD<F32>(b2,colA);
    float bvb = okB ? LD<F32>(b2,colB) : 0.f;
    #pragma unroll
    for(int r=0;r<4;r++){ acc[r][0]=bva; acc[r][1]=bvb; }
  }
  for(int k0=0;k0<HID;k0+=8){
    float wa[8], wb[8];
    #pragma unroll
    for(int u=0;u<8;u++){
      wa[u] = LD<F32>(W2,(size_t)(k0+u)*NGEN + colA);
      wb[u] = okB ? LD<F32>(W2,(size_t)(k0+u)*NGEN + colB) : 0.f;
    }
    #pragma unroll
    for(int u=0;u<8;u++){
      float4 ha = *(const float4*)&hl_t[k0+u][0];
      float fa = wa[u], fb = wb[u];
      acc[0][0]+=ha.x*fa; acc[0][1]+=ha.x*fb;
      acc[1][0]+=ha.y*fa; acc[1][1]+=ha.y*fb;
      acc[2][0]+=ha.z*fa; acc[2][1]+=ha.z*fb;
      acc[3][0]+=ha.w*fa; acc[3][1]+=ha.w*fb;
    }
  }
  #pragma unroll
  for(int r=0;r<4;r++){
    g_theta[(size_t)(b0+r)*NGEN + colA] = acc[r][0];
    if(okB) g_theta[(size_t)(b0+r)*NGEN + colB] = acc[r][1];
  }
}

__global__ __launch_bounds__(256) void k_enc(const void* x,const void* W1,const void* b1,
                                             const void* W2,const void* b2){
  __shared__ __align__(16) float xl_t[INDIM][4];
  __shared__ __align__(16) float hl_t[HID][4];
  if(g_isf32) enc_body<true >(x,W1,b1,W2,b2,xl_t,hl_t);
  else        enc_body<false>(x,W1,b1,W2,b2,xl_t,hl_t);
}

// -------- state evolution + 2-local observables --------
// R15: 128-thread blocks (2 waves).  Thread (i=t>>1, c=t&1) holds row i,
// cols c*32..c*32+31 in hreg[64] (~95 VGPR, fits the 128 class; bounds(128,2)
// caps at 256 -> no spill).  Matvec v-reads are LDS BROADCASTS (address
// independent of i: 2 unique addrs/instr -> conflict-free, no replication);
// reduction is one shfl_xor(.,1); (H/a)e0 = hreg[0..1] at c==0 (compile-time).
// Barriers now involve only 2 waves; HH stride 130 -> LDS 49664 -> 3 blocks/CU,
// 512 blocks <= 768 resident slots -> whole batch ~1 generation.
template<bool F32>
__device__ void state_body(const void* __restrict__ Aoff, const void* __restrict__ Boff,
                           const void* __restrict__ Ddiag, char* sm){
  float*  th   = (float*)sm;                       // 16384 B (dead after WHT)
  float*  HH   = (float*)(sm + 16384);             // 64*130 f = 33280 B
  float2* v0   = (float2*)sm;                      // 512 B  (reuse th region)
  float2* v1   = (float2*)(sm + 512);              // 512 B
  float2* ps   = (float2*)(sm + 1024);             // 512 B
  float2* coef = (float2*)(sm + 1536);             // 1280 B
  float*  rs   = (float*)(sm + 2816);              // 256 B
  float*  qacc = (float*)(sm + 3072);              // 64 B
  float*  s_inva = (float*)(sm + 3136);
  int*    s_K    = (int*)(sm + 3140);

  const int b = blockIdx.x, t = threadIdx.x;       // t in 0..127
  const int lane = t & 63, w2 = t >> 6;            // 2 waves
  for(int m=t;m<NGEN;m+=128) th[m] = g_theta[(size_t)b*NGEN+m];
  __syncthreads();

  // WHT per xor-pattern d (32 patterns per wave): lane gets H[lane][lane^d]
  for(int it=0; it<32; ++it){
    int d = (it<<1) | w2;
    unsigned td = (unsigned)(lane & d);
    unsigned tn = (unsigned)(lane & ~d) & 63u;
    unsigned w  = spread6((unsigned)d) + spread6(td) + 3u*spread6(tn);
    float thv = (w==0u) ? 0.f : th[w-1u];
    int ny = __popc(td) & 3;                       // phase (-i)^|y|
    float gr = (ny==0)?  thv : (ny==2 ? -thv : 0.f);
    float gi = (ny==1)? -thv : (ny==3 ?  thv : 0.f);
    #pragma unroll
    for(int s=1;s<64;s<<=1){
      float pr = __shfl_xor(gr, s);
      float pi = __shfl_xor(gi, s);
      if(lane & s){ gr = pr - gr; gi = pi - gi; }
      else        { gr = gr + pr; gi = gi + pi; }
    }
    int j = lane ^ d;
    HH[lane*130 + 2*j]   = gr;
    HH[lane*130 + 2*j+1] = gi;
  }
  __syncthreads();          // th region dead; small buffers live there now

  // thread (i,c): row i, cols c*32..c*32+31 into hreg[64]; half-row abs-sum
  const int i = t >> 1, c = t & 1, j0 = c*32;
  float hreg[64];
  float rsum = 0.f;
  #pragma unroll
  for(int q=0;q<16;q++){
    float4 hv = *(const float4*)&HH[i*130 + 2*(j0 + 2*q)];
    hreg[4*q+0]=hv.x; hreg[4*q+1]=hv.y; hreg[4*q+2]=hv.z; hreg[4*q+3]=hv.w;
    rsum += fabsf(hv.x)+fabsf(hv.y)+fabsf(hv.z)+fabsf(hv.w);
  }
  rsum += __shfl_xor(rsum,1);
  if(c==0) rs[i] = rsum;
  __syncthreads();

  if(t==0){
    float a = 0.5f;
    for(int r=0;r<DIM;r++) a = fmaxf(a, rs[r]);
    int K = (int)ceilf(a + 6.f*cbrtf(a) + 10.f);
    if(K>150) K=150;
    float bkp=0.f, bk=1e-35f, snorm=0.f;
    for(int k=K+12;k>=1;--k){
      float bkm = (2.f*(float)k/a)*bk - bkp;
      int n = k-1;
      if(n<=K) coef[n].x = bkm;
      if((n&1)==0) snorm += (n==0?1.f:2.f)*bkm;   // J0 + 2*sum J_{2m} = 1
      bkp = bk; bk = bkm;
    }
    float invs = 1.f/snorm;
    for(int n=0;n<=K;n++){
      float cv = coef[n].x*invs*(n==0?1.f:2.f);
      int p = n&3;                                 // i^n
      float cr = (p==0)? cv : (p==2 ? -cv : 0.f);
      float ci = (p==1)? cv : (p==3 ? -cv : 0.f);
      coef[n] = make_float2(cr,ci);
    }
    *s_K = K;
    *s_inva = 1.f/a;
  }
  __syncthreads();
  const float inva = *s_inva;
  const int K = *s_K;

  // init: v0 = e0; v1 = (H/a)e0 (col 0 = hreg[0..1] of c==0 thread); psi
  if(c==0){
    float2 w1 = make_float2(hreg[0]*inva, hreg[1]*inva);
    v0[i] = make_float2(i==0?1.f:0.f, 0.f);
    v1[i] = w1;
    float2 c0v = coef[0], c1v = coef[1];
    float2 p;
    p.x = (i==0?c0v.x:0.f) + c1v.x*w1.x - c1v.y*w1.y;
    p.y = (i==0?c0v.y:0.f) + c1v.x*w1.y + c1v.y*w1.x;
    ps[i] = p;
  }
  __syncthreads();

  float2* vp = v0;   // T_{k-2}
  float2* vc = v1;   // T_{k-1}
  for(int k=2;k<=K;k++){
    const float* vb = (const float*)vc;            // broadcast reads (addr indep of i)
    float yr=0.f, yi=0.f;
    #pragma unroll
    for(int q=0;q<16;q++){
      float4 xv = *(const float4*)&vb[2*(j0 + 2*q)];
      float hr0=hreg[4*q+0], hi0=hreg[4*q+1], hr1=hreg[4*q+2], hi1=hreg[4*q+3];
      yr += hr0*xv.x - hi0*xv.y;
      yi += hr0*xv.y + hi0*xv.x;
      yr += hr1*xv.z - hi1*xv.w;
      yi += hr1*xv.w + hi1*xv.z;
    }
    yr += __shfl_xor(yr,1);
    yi += __shfl_xor(yi,1);
    if(c==0){
      float2 vm = vp[i];
      float2 vn = make_float2(2.f*inva*yr - vm.x, 2.f*inva*yi - vm.y);
      vp[i] = vn;                                  // becomes current after swap
      float2 ck = coef[k];
      float2 p = ps[i];
      p.x += ck.x*vn.x - ck.y*vn.y;
      p.y += ck.x*vn.y + ck.y*vn.x;
      ps[i] = p;
    }
    __syncthreads();
    float2* tmp = vp; vp = vc; vc = tmp;
  }

  if(t<NOBS) qacc[t]=0.f;
  __syncthreads();

  // 2-local observables: 150 tasks over 128 threads
  for(int task=t; task<150; task+=128){
    int w = task/10, s = task%10;
    int posA = 5 - c_WA[w], posB = 5 - c_WB[w];
    if(s<4){
      int kk = s;
      if(kk<3){                                    // H_kk = 2*D[w][kk+1]; H_33 = 0
        float val = 0.f;
        for(int r=0;r<16;r++){
          int idx = (((kk>>1)&1)<<posA) | ((kk&1)<<posB);
          int rb = 3;
          #pragma unroll
          for(int p=5;p>=0;--p){
            if(p==posA || p==posB) continue;
            idx |= ((r>>rb)&1)<<p;
            rb--;
          }
          float2 pv = ps[idx];
          val += pv.x*pv.x + pv.y*pv.y;
        }
        atomicAdd(&qacc[w], val*2.f*LD<F32>(Ddiag, w*4 + kk + 1));
      }
    } else {
      int cc = s-4;
      int l = c_Lt[cc], kk = c_Kt[cc];
      float zr=0.f, zi=0.f;
      for(int r=0;r<16;r++){
        int idxk = (((kk>>1)&1)<<posA) | ((kk&1)<<posB);
        int idxl = (((l >>1)&1)<<posA) | ((l &1)<<posB);
        int rb = 3;
        #pragma unroll
        for(int p=5;p>=0;--p){
          if(p==posA || p==posB) continue;
          int bit = (r>>rb)&1;
          idxk |= bit<<p; idxl |= bit<<p;
          rb--;
        }
        float2 pk = ps[idxk], pl = ps[idxl];
        zr += pk.x*pl.x + pk.y*pl.y;               // rho[kk,l]
        zi += pk.y*pl.x - pk.x*pl.y;
      }
      atomicAdd(&qacc[w], 2.f*(zr*LD<F32>(Aoff,w*6+cc) - zi*LD<F32>(Boff,w*6+cc)));
    }
  }
  __syncthreads();
  if(t<NOBS) g_q[(size_t)b*NOBS + t] = qacc[t];
}

__global__ __launch_bounds__(128, 2) void k_state(const void* Aoff,const void* Boff,const void* Dd){
  __shared__ __align__(16) char sm[49664];   // shared by both template paths
  if(g_isf32) state_body<true >(Aoff,Boff,Dd,sm);
  else        state_body<false>(Aoff,Boff,Dd,sm);
}

// ---------------- vel head (R13 standalone body restored — fusion was neutral) ----------------
template<bool F32>
__device__ void vel_body(const void* __restrict__ Wv1, const void* __restrict__ bv1,
                         const void* __restrict__ Wv2, const void* __restrict__ bv2,
                         void* __restrict__ out){
  __shared__ float ql[NOBS];
  __shared__ float hl[HID];
  const int b = blockIdx.x, t = threadIdx.x;
  if(t<NOBS) ql[t] = g_q[(size_t)b*NOBS+t];
  __syncthreads();
  float acc = LD<F32>(bv1,t);
  #pragma unroll
  for(int k=0;k<NOBS;k++) acc += ql[k]*LD<F32>(Wv1,k*HID+t);
  hl[t] = silu(acc);
  __syncthreads();
  if(F32){
    #pragma unroll
    for(int oo=0;oo<2;oo++){
      int o = t + oo*256;
      float s0=0.f;
      for(int k=0;k<HID;k++) s0 += hl[k]*LD<F32>(Wv2,(size_t)k*OUTDIM+o);
      ((float*)out)[(size_t)b*OUTDIM+o] = LD<F32>(bv2,o) + s0;
    }
  } else {
    const unsigned* w2p = (const unsigned*)Wv2;     // [256][256] pairs, 4B aligned
    float sa=0.f, sb=0.f;
    #pragma unroll 8
    for(int k=0;k<HID;k++){
      unsigned wp = w2p[(size_t)k*(OUTDIM/2) + t];
      float hk = hl[k];
      sa += hk*__uint_as_float(wp<<16);
      sb += hk*__uint_as_float(wp & 0xFFFF0000u);
    }
    float va = tof(((const bf16*)bv2)[2*t  ]) + sa;
    float vb = tof(((const bf16*)bv2)[2*t+1]) + sb;
    bf16 ha = __float2bfloat16(va), hb = __float2bfloat16(vb);
    unsigned pw = (unsigned)(*(unsigned short*)&ha) | ((unsigned)(*(unsigned short*)&hb)<<16);
    ((unsigned*)out)[(size_t)b*(OUTDIM/2) + t] = pw;
  }
}

__global__ __launch_bounds__(256) void k_vel(const void* Wv1,const void* bv1,
                                             const void* Wv2,const void* bv2, void* out){
  if(g_isf32) vel_body<true >(Wv1,bv1,Wv2,bv2,out);
  else        vel_body<false>(Wv1,bv1,Wv2,bv2,out);
}

extern "C" void kernel_launch(void* const* d_in, const int* in_sizes, int n_in,
                              void* d_out, int out_size, void* d_ws, size_t ws_size,
                              hipStream_t stream){
  const void* x    = d_in[0];
  const void* W1   = d_in[1];
  const void* b1   = d_in[2];
  const void* W2   = d_in[3];
  const void* b2   = d_in[4];
  const void* Aoff = d_in[5];
  const void* Boff = d_in[6];
  const void* Dd   = d_in[7];
  const void* Wv1  = d_in[8];
  const void* bv1  = d_in[9];
  const void* Wv2  = d_in[10];
  const void* bv2  = d_in[11];
  // d_in[12] (pauli) unused: H_eff built analytically from the Pauli-word structure.

  k_detect<<<1,256,0,stream>>>((const unsigned*)W1);
  k_enc  <<<1024,256,0,stream>>>(x,W1,b1,W2,b2);
  k_state<<<BATCH,128,0,stream>>>(Aoff,Boff,Dd);
  k_vel  <<<BATCH,256,0,stream>>>(Wv1,bv1,Wv2,bv2,d_out);
}

// Round 16
// 325.641 us; speedup vs baseline: 1.0566x; 1.0566x over previous
//
#include <hip/hip_runtime.h>
#include <hip/hip_bf16.h>

#define BATCH   512
#define INDIM   768
#define HID     256
#define NGEN    4095
#define NGENP   4096
#define NOBS    15
#define OUTDIM  512
#define DIM     64

typedef __hip_bfloat16 bf16;

// static device scratch: no reliance on ws_size
__device__ int      g_isf32;
__device__ float    g_theta[(size_t)BATCH*NGEN];
__device__ float    g_q[BATCH*NOBS];
__device__ __align__(16) unsigned g_W2p[(size_t)HID*(NGENP/2)];  // W2 repacked: 2 bf16/u32

__device__ __forceinline__ float tof(bf16 v){ return __bfloat162float(v); }
__device__ __forceinline__ float silu(float x){ return x / (1.f + __expf(-x)); }
__device__ __forceinline__ float blo(unsigned u){ return __uint_as_float(u<<16); }
__device__ __forceinline__ float bhi(unsigned u){ return __uint_as_float(u & 0xFFFF0000u); }

template<bool F32>
__device__ __forceinline__ float LD(const void* p, size_t i){
  if(F32) return ((const float*)p)[i];
  else    return tof(((const bf16*)p)[i]);
}

// put bit p of x at bit 2p (6-bit input)
__device__ __forceinline__ unsigned spread6(unsigned x){
  return (x&1u) | ((x&2u)<<1) | ((x&4u)<<2) | ((x&8u)<<3) | ((x&16u)<<4) | ((x&32u)<<5);
}

__constant__ int c_WA[15] = {0,0,0,0,0,1,1,1,1,2,2,2,3,3,4};
__constant__ int c_WB[15] = {1,2,3,4,5,2,3,4,5,3,4,5,4,5,5};
__constant__ int c_Lt[6]  = {1,2,2,3,3,3};
__constant__ int c_Kt[6]  = {0,0,1,0,1,2};

// ---- dtype sniffer (UNCHANGED; stays the FIRST kernel) ----
__global__ __launch_bounds__(256) void k_detect(const unsigned* __restrict__ w1raw){
  __shared__ int sh[256];
  const int t = threadIdx.x;
  int c = 0;
  for(int i=t;i<1024;i+=256){
    unsigned ub = (w1raw[i]>>8) & 0x7Fu;
    if(ub>=0x30u && ub<=0x3Fu) c++;
  }
  sh[t] = c;
  __syncthreads();
  for(int s=128;s>0;s>>=1){
    if(t<s) sh[t] += sh[t+s];
    __syncthreads();
  }
  if(t==0) g_isf32 = (sh[0] < 512) ? 1 : 0;
}

// ---- repack W2 [256][4095] bf16 -> [256][2048] u32 (2 bf16/word, aligned) ----
__global__ __launch_bounds__(256) void k_pack(const unsigned short* __restrict__ W2){
  const int k = blockIdx.x;
  const unsigned short* row = W2 + (size_t)k*NGEN;
  unsigned* dst = g_W2p + (size_t)k*(NGENP/2);
  for(int m2=threadIdx.x; m2<NGENP/2; m2+=256){
    unsigned lo = row[2*m2];                               // 2*m2 <= 4094 < NGEN
    unsigned hi = (2*m2+1<NGEN) ? (unsigned)row[2*m2+1] : 0u;
    dst[m2] = lo | (hi<<16);
  }
}

// ---------------- enc MLP: theta = silu(x@W1+b1)@W2+b2 ----------------
// R16 (bf16 path): MLP1 reads W1 as aligned u32 pairs (row stride 256 even),
// split-k over thread halves (384 u32 loads/thread vs 768 scalar), partials
// through 9-float-padded LDS.  MLP2 reads g_W2p u32 pairs (256 loads/thread
// vs 512 scalar).  1024 blocks = 4 rows x 512 cols as R13.
__device__ void enc_bf16(const bf16* __restrict__ x, const unsigned* __restrict__ W1u,
                         const bf16* __restrict__ b1, const bf16* __restrict__ b2,
                         float (*xl_t)[4], float (*hl_t)[4], float (*part)[128][9]){
  const int t  = threadIdx.x;
  const int b0 = (blockIdx.x >> 3) * 4;            // row group 0..127
  #pragma unroll
  for(int r=0;r<4;r++)
    for(int k=t;k<INDIM;k+=256) xl_t[k][r] = tof(((const bf16*)x)[(size_t)(b0+r)*INDIM+k]);
  __syncthreads();

  // ---- MLP1: thread t -> unit pair j=t&127 (units 2j,2j+1), k-half = t>>7 ----
  {
    const int j = t & 127, half = t >> 7;
    float a0[4]={0.f,0.f,0.f,0.f}, a1[4]={0.f,0.f,0.f,0.f};
    for(int k0=half*384; k0<half*384+384; k0+=8){
      unsigned wv[8];
      #pragma unroll
      for(int u=0;u<8;u++) wv[u] = W1u[(size_t)(k0+u)*(HID/2) + j];
      #pragma unroll
      for(int u=0;u<8;u++){
        float fa = blo(wv[u]), fb = bhi(wv[u]);
        float4 xa = *(const float4*)&xl_t[k0+u][0];
        a0[0]+=xa.x*fa; a0[1]+=xa.y*fa; a0[2]+=xa.z*fa; a0[3]+=xa.w*fa;
        a1[0]+=xa.x*fb; a1[1]+=xa.y*fb; a1[2]+=xa.z*fb; a1[3]+=xa.w*fb;
      }
    }
    #pragma unroll
    for(int r=0;r<4;r++){ part[half][j][r]=a0[r]; part[half][j][4+r]=a1[r]; }
  }
  __syncthreads();
  {
    float bb = tof(b1[t]);
    const int j = t>>1, sub = t&1;
    #pragma unroll
    for(int r=0;r<4;r++)
      hl_t[t][r] = silu(bb + part[0][j][sub*4+r] + part[1][j][sub*4+r]);
  }
  __syncthreads();

  // ---- MLP2: thread t -> col pair p2 (cols 2p2, 2p2+1) via g_W2p ----
  const int p2 = (blockIdx.x & 7)*256 + t;         // 0..2047
  const int colA = 2*p2, colB = colA+1;            // colA <= 4094 always valid
  const bool okB = (colB < NGEN);
  float acc[4][2];
  {
    float bva = tof(b2[colA]);
    float bvb = okB ? tof(b2[colB]) : 0.f;
    #pragma unroll
    for(int r=0;r<4;r++){ acc[r][0]=bva; acc[r][1]=bvb; }
  }
  for(int k0=0;k0<HID;k0+=8){
    unsigned wp[8];
    #pragma unroll
    for(int u=0;u<8;u++) wp[u] = g_W2p[(size_t)(k0+u)*(NGENP/2) + p2];
    #pragma unroll
    for(int u=0;u<8;u++){
      float fa = blo(wp[u]), fb = bhi(wp[u]);
      float4 ha = *(const float4*)&hl_t[k0+u][0];
      acc[0][0]+=ha.x*fa; acc[0][1]+=ha.x*fb;
      acc[1][0]+=ha.y*fa; acc[1][1]+=ha.y*fb;
      acc[2][0]+=ha.z*fa; acc[2][1]+=ha.z*fb;
      acc[3][0]+=ha.w*fa; acc[3][1]+=ha.w*fb;
    }
  }
  #pragma unroll
  for(int r=0;r<4;r++){
    g_theta[(size_t)(b0+r)*NGEN + colA] = acc[r][0];
    if(okB) g_theta[(size_t)(b0+r)*NGEN + colB] = acc[r][1];
  }
}

// f32 fallback (never taken on this problem; correctness-only, R13 structure)
__device__ void enc_f32(const float* __restrict__ x, const float* __restrict__ W1,
                        const float* __restrict__ b1, const float* __restrict__ W2,
                        const float* __restrict__ b2,
                        float (*xl_t)[4], float (*hl_t)[4]){
  const int t  = threadIdx.x;
  const int b0 = (blockIdx.x >> 3) * 4;
  const int c0 = (blockIdx.x & 7) * 512;
  #pragma unroll
  for(int r=0;r<4;r++)
    for(int k=t;k<INDIM;k+=256) xl_t[k][r] = x[(size_t)(b0+r)*INDIM+k];
  __syncthreads();
  {
    float acc1[4]={0.f,0.f,0.f,0.f};
    for(int k=0;k<INDIM;k++){
      float w = W1[(size_t)k*HID+t];
      float4 xa = *(const float4*)&xl_t[k][0];
      acc1[0]+=xa.x*w; acc1[1]+=xa.y*w; acc1[2]+=xa.z*w; acc1[3]+=xa.w*w;
    }
    float bb = b1[t];
    #pragma unroll
    for(int r=0;r<4;r++) hl_t[t][r] = silu(acc1[r]+bb);
  }
  __syncthreads();
  const int colA = c0 + t, colB = c0 + 256 + t;
  const bool okB = (colB < NGEN);
  float acc[4][2];
  float bva = b2[colA], bvb = okB ? b2[colB] : 0.f;
  #pragma unroll
  for(int r=0;r<4;r++){ acc[r][0]=bva; acc[r][1]=bvb; }
  for(int k=0;k<HID;k++){
    float wa = W2[(size_t)k*NGEN + colA];
    float wb = okB ? W2[(size_t)k*NGEN + colB] : 0.f;
    float4 ha = *(const float4*)&hl_t[k][0];
    acc[0][0]+=ha.x*wa; acc[0][1]+=ha.x*wb;
    acc[1][0]+=ha.y*wa; acc[1][1]+=ha.y*wb;
    acc[2][0]+=ha.z*wa; acc[2][1]+=ha.z*wb;
    acc[3][0]+=ha.w*wa; acc[3][1]+=ha.w*wb;
  }
  #pragma unroll
  for(int r=0;r<4;r++){
    g_theta[(size_t)(b0+r)*NGEN + colA] = acc[r][0];
    if(okB) g_theta[(size_t)(b0+r)*NGEN + colB] = acc[r][1];
  }
}

__global__ __launch_bounds__(256) void k_enc(const void* x,const void* W1,const void* b1,
                                             const void* W2,const void* b2){
  __shared__ __align__(16) float xl_t[INDIM][4];      // 12288 B
  __shared__ __align__(16) float hl_t[HID][4];        //  4096 B
  __shared__ __align__(16) float part[2][128][9];     //  9216 B
  if(g_isf32) enc_f32((const float*)x,(const float*)W1,(const float*)b1,
                      (const float*)W2,(const float*)b2,xl_t,hl_t);
  else        enc_bf16((const bf16*)x,(const unsigned*)W1,(const bf16*)b1,
                       (const bf16*)b2,xl_t,hl_t,part);
}

// -------- state evolution + 2-local observables (R13 body VERBATIM — proven 113us;
// R15's 2-wave variant hit a same-bank 2-addr conflict on every b128 and regressed) --------
template<bool F32>
__device__ void state_body(const void* __restrict__ Aoff, const void* __restrict__ Boff,
                           const void* __restrict__ Ddiag, char* sm){
  float*  th   = (float*)sm;                       // 4096 f  (dead after WHT)
  float*  HH   = (float*)(sm + 16384);             // 64*132 f
  typedef float2 rep_t[66];
  rep_t*  vrA  = (rep_t*)sm;                       // 2112 B
  rep_t*  vrB  = (rep_t*)(sm + 2112);              // 2112 B
  float2* ps   = (float2*)(sm + 4224);             // 512 B
  float2* coef = (float2*)(sm + 4736);             // 1280 B
  float*  rs   = (float*)(sm + 6016);              // 256 B
  float*  qacc = (float*)(sm + 6272);              // 64 B
  float*  s_inva = (float*)(sm + 6336);
  int*    s_K    = (int*)(sm + 6340);

  const int b = blockIdx.x, t = threadIdx.x;
  for(int m=t;m<NGEN;m+=256) th[m] = g_theta[(size_t)b*NGEN+m];
  __syncthreads();

  const int lane = t & 63, wav = t >> 6;
  for(int it=0; it<16; ++it){
    int d = (it<<2) | wav;
    unsigned td = (unsigned)(lane & d);
    unsigned tn = (unsigned)(lane & ~d) & 63u;
    unsigned w  = spread6((unsigned)d) + spread6(td) + 3u*spread6(tn);
    float thv = (w==0u) ? 0.f : th[w-1u];
    int ny = __popc(td) & 3;
    float gr = (ny==0)?  thv : (ny==2 ? -thv : 0.f);
    float gi = (ny==1)? -thv : (ny==3 ?  thv : 0.f);
    #pragma unroll
    for(int s=1;s<64;s<<=1){
      float pr = __shfl_xor(gr, s);
      float pi = __shfl_xor(gi, s);
      if(lane & s){ gr = pr - gr; gi = pi - gi; }
      else        { gr = gr + pr; gi = gi + pi; }
    }
    int j = lane ^ d;
    HH[lane*132 + 2*j]   = gr;
    HH[lane*132 + 2*j+1] = gi;
  }
  __syncthreads();          // th dead from here

  const int i = t >> 2, c = t & 3, j0 = c*16;
  float hreg[32];
  float rsum = 0.f;
  #pragma unroll
  for(int jj=0;jj<16;jj+=2){
    float4 hv = *(const float4*)&HH[i*132 + 2*(j0+jj)];
    hreg[2*jj+0]=hv.x; hreg[2*jj+1]=hv.y; hreg[2*jj+2]=hv.z; hreg[2*jj+3]=hv.w;
    rsum += fabsf(hv.x)+fabsf(hv.y)+fabsf(hv.z)+fabsf(hv.w);
  }
  rsum += __shfl_xor(rsum,1);
  rsum += __shfl_xor(rsum,2);
  if(c==0) rs[i] = rsum;
  __syncthreads();

  if(t==0){
    float a = 0.5f;
    for(int r=0;r<DIM;r++) a = fmaxf(a, rs[r]);
    int K = (int)ceilf(a + 6.f*cbrtf(a) + 10.f);
    if(K>150) K=150;
    float bkp=0.f, bk=1e-35f, snorm=0.f;
    for(int k=K+12;k>=1;--k){
      float bkm = (2.f*(float)k/a)*bk - bkp;
      int n = k-1;
      if(n<=K) coef[n].x = bkm;
      if((n&1)==0) snorm += (n==0?1.f:2.f)*bkm;
      bkp = bk; bk = bkm;
    }
    float invs = 1.f/snorm;
    for(int n=0;n<=K;n++){
      float cv = coef[n].x*invs*(n==0?1.f:2.f);
      int p = n&3;
      float cr = (p==0)? cv : (p==2 ? -cv : 0.f);
      float ci = (p==1)? cv : (p==3 ? -cv : 0.f);
      coef[n] = make_float2(cr,ci);
    }
    *s_K = K;
    *s_inva = 1.f/a;
  }
  __syncthreads();
  const float inva = *s_inva;
  const int K = *s_K;

  rep_t* v0r = vrA;
  rep_t* v1r = vrB;
  if(t < DIM){
    float2 w1 = make_float2(HH[t*132+0]*inva, HH[t*132+1]*inva);
    float2 e0 = make_float2(t==0?1.f:0.f, 0.f);
    #pragma unroll
    for(int cc=0;cc<4;cc++){ v0r[cc][t] = e0; v1r[cc][t] = w1; }
    float2 c0 = coef[0], c1 = coef[1];
    float2 p;
    p.x = (t==0?c0.x:0.f) + c1.x*w1.x - c1.y*w1.y;
    p.y = (t==0?c0.y:0.f) + c1.x*w1.y + c1.y*w1.x;
    ps[t] = p;
  }
  __syncthreads();

  for(int k=2;k<=K;k++){
    const float* vb = (const float*)&v1r[c][0];
    float yr=0.f, yi=0.f;
    #pragma unroll
    for(int jj=0;jj<16;jj+=2){
      float4 xv = *(const float4*)&vb[2*(j0+jj)];
      float hr0=hreg[2*jj], hi0=hreg[2*jj+1], hr1=hreg[2*jj+2], hi1=hreg[2*jj+3];
      yr += hr0*xv.x - hi0*xv.y;
      yi += hr0*xv.y + hi0*xv.x;
      yr += hr1*xv.z - hi1*xv.w;
      yi += hr1*xv.w + hi1*xv.z;
    }
    yr += __shfl_xor(yr,1); yr += __shfl_xor(yr,2);
    yi += __shfl_xor(yi,1); yi += __shfl_xor(yi,2);
    if(c==0){
      float2 vm = v0r[0][i];
      float2 vn = make_float2(2.f*inva*yr - vm.x, 2.f*inva*yi - vm.y);
      #pragma unroll
      for(int cc=0;cc<4;cc++) v0r[cc][i] = vn;
      float2 ck = coef[k];
      float2 p = ps[i];
      p.x += ck.x*vn.x - ck.y*vn.y;
      p.y += ck.x*vn.y + ck.y*vn.x;
      ps[i] = p;
    }
    __syncthreads();
    rep_t* tmp = v0r; v0r = v1r; v1r = tmp;
  }

  if(t<NOBS) qacc[t]=0.f;
  __syncthreads();

  if(t<150){
    int w = t/10, s = t%10;
    int posA = 5 - c_WA[w], posB = 5 - c_WB[w];
    float contrib = 0.f;
    bool have = false;
    if(s<4){
      int kk = s;
      if(kk<3){
        float val = 0.f;
        for(int r=0;r<16;r++){
          int idx = (((kk>>1)&1)<<posA) | ((kk&1)<<posB);
          int rb = 3;
          #pragma unroll
          for(int p=5;p>=0;--p){
            if(p==posA || p==posB) continue;
            idx |= ((r>>rb)&1)<<p;
            rb--;
          }
          float2 pv = ps[idx];
          val += pv.x*pv.x + pv.y*pv.y;
        }
        contrib = val*2.f*LD<F32>(Ddiag, w*4 + kk + 1);
        have = true;
      }
    } else {
      int cc = s-4;
      int l = c_Lt[cc], kk = c_Kt[cc];
      float zr=0.f, zi=0.f;
      for(int r=0;r<16;r++){
        int idxk = (((kk>>1)&1)<<posA) | ((kk&1)<<posB);
        int idxl = (((l >>1)&1)<<posA) | ((l &1)<<posB);
        int rb = 3;
        #pragma unroll
        for(int p=5;p>=0;--p){
          if(p==posA || p==posB) continue;
          int bit = (r>>rb)&1;
          idxk |= bit<<p; idxl |= bit<<p;
          rb--;
        }
        float2 pk = ps[idxk], pl = ps[idxl];
        zr += pk.x*pl.x + pk.y*pl.y;
        zi += pk.y*pl.x - pk.x*pl.y;
      }
      contrib = 2.f*(zr*LD<F32>(Aoff,w*6+cc) - zi*LD<F32>(Boff,w*6+cc));
      have = true;
    }
    if(have) atomicAdd(&qacc[w], contrib);
  }
  __syncthreads();
  if(t<NOBS) g_q[(size_t)b*NOBS + t] = qacc[t];
}

__global__ __launch_bounds__(256) void k_state(const void* Aoff,const void* Boff,const void* Dd){
  __shared__ __align__(16) char sm[50176];   // shared by both template paths
  if(g_isf32) state_body<true >(Aoff,Boff,Dd,sm);
  else        state_body<false>(Aoff,Boff,Dd,sm);
}

// ---------------- vel head (UNCHANGED R13 standalone) ----------------
template<bool F32>
__device__ void vel_body(const void* __restrict__ Wv1, const void* __restrict__ bv1,
                         const void* __restrict__ Wv2, const void* __restrict__ bv2,
                         void* __restrict__ out){
  __shared__ float ql[NOBS];
  __shared__ float hl[HID];
  const int b = blockIdx.x, t = threadIdx.x;
  if(t<NOBS) ql[t] = g_q[(size_t)b*NOBS+t];
  __syncthreads();
  float acc = LD<F32>(bv1,t);
  #pragma unroll
  for(int k=0;k<NOBS;k++) acc += ql[k]*LD<F32>(Wv1,k*HID+t);
  hl[t] = silu(acc);
  __syncthreads();
  if(F32){
    #pragma unroll
    for(int oo=0;oo<2;oo++){
      int o = t + oo*256;
      float s0=0.f;
      for(int k=0;k<HID;k++) s0 += hl[k]*LD<F32>(Wv2,(size_t)k*OUTDIM+o);
      ((float*)out)[(size_t)b*OUTDIM+o] = LD<F32>(bv2,o) + s0;
    }
  } else {
    const unsigned* w2p = (const unsigned*)Wv2;     // [256][256] pairs, 4B aligned
    float sa=0.f, sb=0.f;
    #pragma unroll 8
    for(int k=0;k<HID;k++){
      unsigned wp = w2p[(size_t)k*(OUTDIM/2) + t];
      float hk = hl[k];
      sa += hk*__uint_as_float(wp<<16);
      sb += hk*__uint_as_float(wp & 0xFFFF0000u);
    }
    float va = tof(((const bf16*)bv2)[2*t  ]) + sa;
    float vb = tof(((const bf16*)bv2)[2*t+1]) + sb;
    bf16 ha = __float2bfloat16(va), hb = __float2bfloat16(vb);
    unsigned pw = (unsigned)(*(unsigned short*)&ha) | ((unsigned)(*(unsigned short*)&hb)<<16);
    ((unsigned*)out)[(size_t)b*(OUTDIM/2) + t] = pw;
  }
}

__global__ __launch_bounds__(256) void k_vel(const void* Wv1,const void* bv1,
                                             const void* Wv2,const void* bv2, void* out){
  if(g_isf32) vel_body<true >(Wv1,bv1,Wv2,bv2,out);
  else        vel_body<false>(Wv1,bv1,Wv2,bv2,out);
}

extern "C" void kernel_launch(void* const* d_in, const int* in_sizes, int n_in,
                              void* d_out, int out_size, void* d_ws, size_t ws_size,
                              hipStream_t stream){
  const void* x    = d_in[0];
  const void* W1   = d_in[1];
  const void* b1   = d_in[2];
  const void* W2   = d_in[3];
  const void* b2   = d_in[4];
  const void* Aoff = d_in[5];
  const void* Boff = d_in[6];
  const void* Dd   = d_in[7];
  const void* Wv1  = d_in[8];
  const void* bv1  = d_in[9];
  const void* Wv2  = d_in[10];
  const void* bv2  = d_in[11];
  // d_in[12] (pauli) unused: H_eff built analytically from the Pauli-word structure.

  k_detect<<<1,256,0,stream>>>((const unsigned*)W1);
  k_pack  <<<HID,256,0,stream>>>((const unsigned short*)W2);
  k_enc   <<<1024,256,0,stream>>>(x,W1,b1,W2,b2);
  k_state <<<BATCH,256,0,stream>>>(Aoff,Boff,Dd);
  k_vel   <<<BATCH,256,0,stream>>>(Wv1,bv1,Wv2,bv2,d_out);
}